// Round 10
// baseline (225.195 us; speedup 1.0000x reference)
//
#include <hip/hip_runtime.h>

// GCN layer: out = Ahat @ x @ W^T + bias, Ahat = D^-1/2 (A + I) D^-1/2
// Pipeline (3 dispatches, no memset): k_bin (512t): self-initializing bucket
// binning by dst>>8 (bin block b zeroes gcnt[b] at entry + MAGIC flag;
// per-bucket gof atomics spin-gate on the flag) -> k_gemmcnt: per-bucket
// 64-dest LDS histogram (fused with tile staging) + y'=rsqrt(deg+1)*(x@W^T)
// via bf16 MFMA; also clears flags for the next replay -> k_aggr (proven
// 53.7us body): LDS counting-sort by dst&255 + per-dest gather, dest scale
// rsqrtf(len+1).
// R10: R9's split reverted (cost +9.7us = ~10us/dispatch boundary). R8 kept
// byte-identical except the memset node is folded into k_bin via
// self-init + flag-gated offsets: 4 nodes -> 3, one boundary removed.

#define NBMAX 400
#define CAP   5120   // bucket capacity: mean 4096 + 16 sigma (sigma ~ 64)
#define MAGIC 0x5EED5EEDu

typedef short bf16x8 __attribute__((ext_vector_type(8)));
typedef float f32x4  __attribute__((ext_vector_type(4)));

__device__ inline float bflo(unsigned u) { return __uint_as_float(u << 16); }
__device__ inline float bfhi(unsigned u) { return __uint_as_float(u & 0xFFFF0000u); }
__device__ inline unsigned short f2bf(float f) {           // round-nearest-even
    unsigned u = __float_as_uint(f);
    u += 0x7FFFu + ((u >> 16) & 1u);
    return (unsigned short)(u >> 16);
}

// Chunk-local LDS counting sort by bucket (dst>>8); contiguous run copy-out of
// packed (src | (dst&255)<<24) records into fixed-stride bucket regions.
// 512 threads: 8 edges/thread; 8 waves overlap each latency phase (R7).
// Self-init: block b (b<NB) zeroes gcnt[b] at entry, then publishes
// flags[b]=MAGIC (device-scope). The gof-phase atomicAdd on gcnt[q] spins
// until flags[q]==MAGIC. Deadlock-free: owners zero at entry; >=1024 blocks
// co-resident >> 391 spinners; flags are cleared by k_gemmcnt each iteration
// so stale MAGIC never survives a replay.
__global__ __launch_bounds__(512) void k_bin(const int* __restrict__ row,
                                             const int* __restrict__ col,
                                             int* __restrict__ gcnt,
                                             unsigned int* __restrict__ flags,
                                             unsigned int* __restrict__ ebuf,
                                             int E, int NB) {
    __shared__ unsigned int   sorted4[4096];   // 16 KB packed records
    __shared__ unsigned short sbkt[4096];      //  8 KB bucket id per slot
    __shared__ int h[NBMAX], hstart[NBMAX], hcur[NBMAX], gof[NBMAX];
    int t = threadIdx.x;
    if (t == 0) {                              // self-init of this block's bucket
        int bb = blockIdx.x;
        if (bb < NB) {
            gcnt[bb] = 0;
            __threadfence();
            atomicExch(&flags[bb], MAGIC);
        }
        if (bb == 0) {                         // tail guard (nbE < NB case)
            for (int q = (int)gridDim.x; q < NB; ++q) {
                gcnt[q] = 0;
                __threadfence();
                atomicExch(&flags[q], MAGIC);
            }
        }
    }
    int base = blockIdx.x * 4096;
    int total = min(4096, E - base);

    int rr[8], cc[8];
    #pragma unroll
    for (int i = 0; i < 2; ++i) {
        int e0 = (t + i * 512) * 4;
        if (e0 + 3 < total) {
            int4 r4 = *(const int4*)(row + base + e0);
            int4 c4 = *(const int4*)(col + base + e0);
            rr[i*4+0]=r4.x; rr[i*4+1]=r4.y; rr[i*4+2]=r4.z; rr[i*4+3]=r4.w;
            cc[i*4+0]=c4.x; cc[i*4+1]=c4.y; cc[i*4+2]=c4.z; cc[i*4+3]=c4.w;
        } else {
            #pragma unroll
            for (int j = 0; j < 4; ++j) {
                int e = e0 + j;
                if (e < total) { rr[i*4+j] = row[base+e]; cc[i*4+j] = col[base+e]; }
                else cc[i*4+j] = -1;
            }
        }
    }
    for (int b = t; b < NBMAX; b += 512) h[b] = 0;
    __syncthreads();
    #pragma unroll
    for (int i = 0; i < 8; ++i)
        if (cc[i] >= 0) atomicAdd(&h[cc[i] >> 8], 1);
    __syncthreads();
    if (t < 64) {                              // wave-0 scan of h
        int lo = t * 7;
        int loc[7]; int s = 0;
        #pragma unroll
        for (int i = 0; i < 7; ++i) {
            loc[i] = s;
            int idx = lo + i;
            s += (idx < NBMAX) ? h[idx] : 0;
        }
        int incl = s;
        for (int off = 1; off < 64; off <<= 1) {
            int v = __shfl_up(incl, off);
            if (t >= off) incl += v;
        }
        int ex = incl - s;
        #pragma unroll
        for (int i = 0; i < 7; ++i) {
            int idx = lo + i;
            if (idx < NBMAX) hstart[idx] = ex + loc[i];
        }
    }
    __syncthreads();
    for (int b = t; b < NBMAX; b += 512) hcur[b] = hstart[b];
    __syncthreads();
    #pragma unroll
    for (int i = 0; i < 8; ++i) {
        if (cc[i] >= 0) {
            int b = cc[i] >> 8;
            int rank = atomicAdd(&hcur[b], 1);
            sorted4[rank] = (unsigned)rr[i] | ((unsigned)(cc[i] & 255) << 24);
            sbkt[rank] = (unsigned short)b;
        }
    }
    for (int b = t; b < NBMAX; b += 512) {
        int m = h[b];
        int go = b * CAP;
        if (m) {                               // spin-gate: bucket b zeroed?
            while (atomicAdd(&flags[b], 0u) != MAGIC) __builtin_amdgcn_s_sleep(8);
            __threadfence();
            go += atomicAdd(&gcnt[b], m);
        }
        gof[b] = go;
    }
    __syncthreads();
    for (int i = t; i < total; i += 512) {     // contiguous per-bucket runs
        int b = sbkt[i];
        ebuf[gof[b] + (i - hstart[b])] = sorted4[i];
    }
}

// y' = rsqrt(deg+1) * (x @ W^T) via bf16 MFMA 16x16x32; 64 rows per block.
// Degree histogram for this block's 64 rows computed in-kernel from the
// bucket's ebuf run (coalesced, L2/L3-hot, overlaps the tile staging loads).
// Also clears flags[] so the next replay's k_bin never sees stale MAGIC.
__global__ __launch_bounds__(256) void k_gemmcnt(const float* __restrict__ x,
                                                 const float* __restrict__ W,
                                                 const unsigned int* __restrict__ ebuf,
                                                 const int* __restrict__ gcnt,
                                                 unsigned int* __restrict__ flags,
                                                 unsigned short* __restrict__ yb, int n) {
    __shared__ __align__(16) unsigned short xs[64][72];
    __shared__ __align__(16) unsigned short Wb[64][72];
    __shared__ int hd[64];
    int t = threadIdx.x;
    long long total = (long long)n * 64;
    long long xbase = (long long)blockIdx.x * 4096;
    if (t == 0 && (blockIdx.x & 3) == 0) {     // clear flag for next replay
        int q = blockIdx.x >> 2;
        if (q < NBMAX) flags[q] = 0u;
    }
    if (t < 64) hd[t] = 0;
    #pragma unroll
    for (int i = 0; i < 4; ++i) {
        int idx = t + i * 256;                 // float4 index 0..1023
        int r = idx >> 4, c4 = (idx & 15) << 2;
        long long g = xbase + (long long)idx * 4;
        float4 v;
        if (g + 3 < total) v = *(const float4*)(x + g);
        else {
            v.x = (g + 0 < total) ? x[g + 0] : 0.f;
            v.y = (g + 1 < total) ? x[g + 1] : 0.f;
            v.z = (g + 2 < total) ? x[g + 2] : 0.f;
            v.w = (g + 3 < total) ? x[g + 3] : 0.f;
        }
        ushort4 o; o.x = f2bf(v.x); o.y = f2bf(v.y); o.z = f2bf(v.z); o.w = f2bf(v.w);
        *(ushort4*)&xs[r][c4] = o;
        float4 wv = *(const float4*)(W + idx * 4);     // W: 4096 floats
        ushort4 wo; wo.x = f2bf(wv.x); wo.y = f2bf(wv.y); wo.z = f2bf(wv.z); wo.w = f2bf(wv.w);
        *(ushort4*)&Wb[r][c4] = wo;
    }
    {   // degree hist for this block's 64 dests (sub-quarter of the bucket)
        int bb  = blockIdx.x >> 2;             // bucket
        int sub = blockIdx.x & 3;              // which 64-dest quarter
        int s0 = bb * CAP;
        int count = min(gcnt[bb], CAP);
        for (int i = t; i < count; i += 256) {
            unsigned d = ebuf[s0 + i] >> 24;
            if ((int)(d >> 6) == sub) atomicAdd(&hd[d & 63], 1);
        }
    }
    __syncthreads();
    int lane = t & 63, wid = t >> 6;
    int m  = wid * 16 + (lane & 15);
    int kg = (lane >> 4) * 8;
    bf16x8 a0 = *(bf16x8*)&xs[m][kg];
    bf16x8 a1 = *(bf16x8*)&xs[m][32 + kg];
    int bn = lane & 15;
    f32x4 acc0 = {0.f,0.f,0.f,0.f}, acc1 = acc0, acc2 = acc0, acc3 = acc0;
    {
        bf16x8 b0 = *(bf16x8*)&Wb[bn][kg], b1 = *(bf16x8*)&Wb[bn][32 + kg];
        acc0 = __builtin_amdgcn_mfma_f32_16x16x32_bf16(a0, b0, acc0, 0, 0, 0);
        acc0 = __builtin_amdgcn_mfma_f32_16x16x32_bf16(a1, b1, acc0, 0, 0, 0);
    }
    {
        bf16x8 b0 = *(bf16x8*)&Wb[bn + 16][kg], b1 = *(bf16x8*)&Wb[bn + 16][32 + kg];
        acc1 = __builtin_amdgcn_mfma_f32_16x16x32_bf16(a0, b0, acc1, 0, 0, 0);
        acc1 = __builtin_amdgcn_mfma_f32_16x16x32_bf16(a1, b1, acc1, 0, 0, 0);
    }
    {
        bf16x8 b0 = *(bf16x8*)&Wb[bn + 32][kg], b1 = *(bf16x8*)&Wb[bn + 32][32 + kg];
        acc2 = __builtin_amdgcn_mfma_f32_16x16x32_bf16(a0, b0, acc2, 0, 0, 0);
        acc2 = __builtin_amdgcn_mfma_f32_16x16x32_bf16(a1, b1, acc2, 0, 0, 0);
    }
    {
        bf16x8 b0 = *(bf16x8*)&Wb[bn + 48][kg], b1 = *(bf16x8*)&Wb[bn + 48][32 + kg];
        acc3 = __builtin_amdgcn_mfma_f32_16x16x32_bf16(a0, b0, acc3, 0, 0, 0);
        acc3 = __builtin_amdgcn_mfma_f32_16x16x32_bf16(a1, b1, acc3, 0, 0, 0);
    }
    // C/D layout: col = lane&15, row = (lane>>4)*4 + reg  [m89-verified]
    int lr0 = wid * 16 + (lane >> 4) * 4;
    int rbase = blockIdx.x * 64 + lr0;
    #pragma unroll
    for (int i = 0; i < 4; ++i) {
        int r = rbase + i;
        if (r < n) {
            float dv = rsqrtf((float)hd[lr0 + i] + 1.0f);
            long long ro = (long long)r * 64 + bn;
            yb[ro +  0] = f2bf(dv * acc0[i]);
            yb[ro + 16] = f2bf(dv * acc1[i]);
            yb[ro + 32] = f2bf(dv * acc2[i]);
            yb[ro + 48] = f2bf(dv * acc3[i]);
        }
    }
}

// FUSED sort+gather: one 1024-thread block per bucket. LDS counting sort by
// dst&255 (sbuf never leaves LDS); then each 16-lane group gathers one dest's
// src list (broadcast ds_read) and writes out directly. Dest scale computed
// locally: dc = rsqrtf(len+1).
__global__ __launch_bounds__(1024) void k_aggr(const unsigned int* __restrict__ ebuf,
                                               const int* __restrict__ gcnt,
                                               const unsigned short* __restrict__ yb,
                                               const float* __restrict__ bias,
                                               float* __restrict__ out, int n) {
    __shared__ int h[256], hstart[256], hc[256], wsum[4];
    __shared__ int sbuf[CAP];                  // 20 KB, LDS-only
    int b = blockIdx.x, t = threadIdx.x;
    int s0 = b * CAP;
    int count = min(gcnt[b], CAP);

    if (t < 256) h[t] = 0;
    __syncthreads();
    unsigned rec[5];
    #pragma unroll
    for (int k = 0; k < 5; ++k) {              // coalesced load + LDS hist
        int i = t + k * 1024;
        if (i < count) {
            unsigned p = ebuf[s0 + i];
            rec[k] = p;
            atomicAdd(&h[p >> 24], 1);
        }
    }
    __syncthreads();
    if (t < 256) {                             // wave-shfl inclusive scan
        int v = h[t];
        int lane = t & 63, wid = t >> 6;
        int incl = v;
        #pragma unroll
        for (int off = 1; off < 64; off <<= 1) {
            int u = __shfl_up(incl, off);
            if (lane >= off) incl += u;
        }
        hstart[t] = incl;                      // temp: inclusive
        if (lane == 63) wsum[wid] = incl;
    }
    __syncthreads();
    if (t < 256) {
        int wid = t >> 6;
        int add = 0;
        for (int w = 0; w < wid; ++w) add += wsum[w];
        int ex = hstart[t] - h[t] + add;       // exclusive prefix
        hstart[t] = ex;
        hc[t] = ex;
    }
    __syncthreads();
    #pragma unroll
    for (int k = 0; k < 5; ++k) {              // counting-sort scatter (LDS)
        int i = t + k * 1024;
        if (i < count) {
            unsigned p = rec[k];
            int r = atomicAdd(&hc[p >> 24], 1);
            sbuf[r] = (int)(p & 0x1FFFFu);
        }
    }
    __syncthreads();

    // Gather: 16 waves x 4 groups = 64 dest-slots; 4 rounds cover 256 dests.
    int lane = t & 63, w = t >> 6;
    int g = lane >> 4, q = lane & 15;
    #pragma unroll
    for (int r = 0; r < 4; ++r) {
        int cl = r * 64 + w * 4 + g;
        int c = b * 256 + cl;
        if (c >= n) continue;                  // no barriers below: safe
        int start = hstart[cl], len = h[cl];
        float a0 = 0.f, a1 = 0.f, a2 = 0.f, a3 = 0.f;
        if (len > 0) {
            int sc = sbuf[start];              // prefetched src
            for (int i = 0; i < len; ++i) {
                int sn = (i + 1 < len) ? sbuf[start + i + 1] : 0;
                float2 v = *(const float2*)(yb + (long long)sc * 64 + (q << 2));
                unsigned u0 = __float_as_uint(v.x), u1 = __float_as_uint(v.y);
                a0 += bflo(u0); a1 += bfhi(u0);
                a2 += bflo(u1); a3 += bfhi(u1);
                sc = sn;
            }
        }
        {   // self loop
            float2 v = *(const float2*)(yb + (long long)c * 64 + (q << 2));
            unsigned u0 = __float_as_uint(v.x), u1 = __float_as_uint(v.y);
            a0 += bflo(u0); a1 += bfhi(u0);
            a2 += bflo(u1); a3 += bfhi(u1);
        }
        float dc = rsqrtf((float)len + 1.0f);
        float4 bv = *(const float4*)(bias + (q << 2));
        *(float4*)(out + (long long)c * 64 + (q << 2)) =
            make_float4(dc * a0 + bv.x, dc * a1 + bv.y,
                        dc * a2 + bv.z, dc * a3 + bv.w);
    }
}

extern "C" void kernel_launch(void* const* d_in, const int* in_sizes, int n_in,
                              void* d_out, int out_size, void* d_ws, size_t ws_size,
                              hipStream_t stream) {
    const float* x    = (const float*)d_in[0];
    const int*   ei   = (const int*)d_in[1];
    // d_in[2] = x0 (unused: use_init=False)
    const float* W    = (const float*)d_in[3];
    const float* bias = (const float*)d_in[4];
    float* out = (float*)d_out;

    int n = in_sizes[0] / 64;
    int E = in_sizes[1] / 2;
    const int* row = ei;        // source
    const int* col = ei + E;    // target

    int NB = (n + 255) / 256;   // 391 (<= NBMAX, <= 512)

    char* ws = (char*)d_ws;
    size_t off = 0;
    auto alloc = [&](size_t bytes) { char* p = ws + off; off += (bytes + 15) & ~size_t(15); return p; };
    int*            gcnt  = (int*)alloc((size_t)NB * 4);
    unsigned int*   flags = (unsigned int*)alloc((size_t)NBMAX * 4);
    unsigned short* yb    = (unsigned short*)alloc((size_t)n * 64 * 2);
    unsigned int*   ebuf  = (unsigned int*)alloc((size_t)NB * CAP * 4);

    int nbE = (E + 4095) / 4096;               // 391

    k_bin    <<<nbE, 512, 0, stream>>>(row, col, gcnt, flags, ebuf, E, NB);
    k_gemmcnt<<<(n + 63) / 64, 256, 0, stream>>>(x, W, ebuf, gcnt, flags, yb, n);
    k_aggr   <<<NB, 1024, 0, stream>>>(ebuf, gcnt, yb, bias, out, n);
}

// Round 11
// 173.013 us; speedup vs baseline: 1.3016x; 1.3016x over previous
//
#include <hip/hip_runtime.h>

// GCN layer: out = Ahat @ x @ W^T + bias, Ahat = D^-1/2 (A + I) D^-1/2
// Pipeline (4 dispatches): memset(gcnt) -> k_bin (512t, R7-proven): bucket
// binning by dst>>8, LDS counting sort, contiguous run writes -> k_gemmcnt
// (512t/128 rows): per-bucket 128-dest LDS histogram (fused with tile
// staging, 2 blocks/bucket) + y' = rsqrt(deg+1)*(x@W^T) via bf16 MFMA ->
// k_aggr (proven 53.7us body): LDS counting-sort by dst&255 + per-dest
// gather, dest scale rsqrtf(len+1).
// R11: R10's spin-gate reverted (75us k_bin, VALUBusy 1% - device-scope
// spins are toxic). Base = R8 (176.0 best). Single change: gemmcnt at
// 512t/128rows - halves block count, hist redundancy (4x->2x), W-conversion
// redundancy, and per-block fixed costs. Same MFMA volume.

#define NBMAX 400
#define CAP   5120   // bucket capacity: mean 4096 + 16 sigma (sigma ~ 64)

typedef short bf16x8 __attribute__((ext_vector_type(8)));
typedef float f32x4  __attribute__((ext_vector_type(4)));

__device__ inline float bflo(unsigned u) { return __uint_as_float(u << 16); }
__device__ inline float bfhi(unsigned u) { return __uint_as_float(u & 0xFFFF0000u); }
__device__ inline unsigned short f2bf(float f) {           // round-nearest-even
    unsigned u = __float_as_uint(f);
    u += 0x7FFFu + ((u >> 16) & 1u);
    return (unsigned short)(u >> 16);
}

// Chunk-local LDS counting sort by bucket (dst>>8); contiguous run copy-out of
// packed (src | (dst&255)<<24) records into fixed-stride bucket regions.
// 512 threads: 8 edges/thread; 8 waves overlap each latency phase (R7).
// gcnt[b] zeroed by memset; region base = b*CAP.
__global__ __launch_bounds__(512) void k_bin(const int* __restrict__ row,
                                             const int* __restrict__ col,
                                             int* __restrict__ gcnt,
                                             unsigned int* __restrict__ ebuf, int E) {
    __shared__ unsigned int   sorted4[4096];   // 16 KB packed records
    __shared__ unsigned short sbkt[4096];      //  8 KB bucket id per slot
    __shared__ int h[NBMAX], hstart[NBMAX], hcur[NBMAX], gof[NBMAX];
    int t = threadIdx.x;
    int base = blockIdx.x * 4096;
    int total = min(4096, E - base);

    int rr[8], cc[8];
    #pragma unroll
    for (int i = 0; i < 2; ++i) {
        int e0 = (t + i * 512) * 4;
        if (e0 + 3 < total) {
            int4 r4 = *(const int4*)(row + base + e0);
            int4 c4 = *(const int4*)(col + base + e0);
            rr[i*4+0]=r4.x; rr[i*4+1]=r4.y; rr[i*4+2]=r4.z; rr[i*4+3]=r4.w;
            cc[i*4+0]=c4.x; cc[i*4+1]=c4.y; cc[i*4+2]=c4.z; cc[i*4+3]=c4.w;
        } else {
            #pragma unroll
            for (int j = 0; j < 4; ++j) {
                int e = e0 + j;
                if (e < total) { rr[i*4+j] = row[base+e]; cc[i*4+j] = col[base+e]; }
                else cc[i*4+j] = -1;
            }
        }
    }
    for (int b = t; b < NBMAX; b += 512) h[b] = 0;
    __syncthreads();
    #pragma unroll
    for (int i = 0; i < 8; ++i)
        if (cc[i] >= 0) atomicAdd(&h[cc[i] >> 8], 1);
    __syncthreads();
    if (t < 64) {                              // wave-0 scan of h
        int lo = t * 7;
        int loc[7]; int s = 0;
        #pragma unroll
        for (int i = 0; i < 7; ++i) {
            loc[i] = s;
            int idx = lo + i;
            s += (idx < NBMAX) ? h[idx] : 0;
        }
        int incl = s;
        for (int off = 1; off < 64; off <<= 1) {
            int v = __shfl_up(incl, off);
            if (t >= off) incl += v;
        }
        int ex = incl - s;
        #pragma unroll
        for (int i = 0; i < 7; ++i) {
            int idx = lo + i;
            if (idx < NBMAX) hstart[idx] = ex + loc[i];
        }
    }
    __syncthreads();
    for (int b = t; b < NBMAX; b += 512) hcur[b] = hstart[b];
    __syncthreads();
    #pragma unroll
    for (int i = 0; i < 8; ++i) {
        if (cc[i] >= 0) {
            int b = cc[i] >> 8;
            int rank = atomicAdd(&hcur[b], 1);
            sorted4[rank] = (unsigned)rr[i] | ((unsigned)(cc[i] & 255) << 24);
            sbkt[rank] = (unsigned short)b;
        }
    }
    for (int b = t; b < NBMAX; b += 512) {
        int m = h[b];
        gof[b] = b * CAP + (m ? atomicAdd(&gcnt[b], m) : 0);
    }
    __syncthreads();
    for (int i = t; i < total; i += 512) {     // contiguous per-bucket runs
        int b = sbkt[i];
        ebuf[gof[b] + (i - hstart[b])] = sorted4[i];
    }
}

// y' = rsqrt(deg+1) * (x @ W^T) via bf16 MFMA 16x16x32; 128 rows per block,
// 512 threads / 8 waves. Degree histogram for this block's 128 rows computed
// in-kernel from the bucket's ebuf run (2 blocks per bucket, coalesced,
// L2/L3-hot, overlaps the tile staging loads). LDS rows padded to 72 bf16.
__global__ __launch_bounds__(512) void k_gemmcnt(const float* __restrict__ x,
                                                 const float* __restrict__ W,
                                                 const unsigned int* __restrict__ ebuf,
                                                 const int* __restrict__ gcnt,
                                                 unsigned short* __restrict__ yb, int n) {
    __shared__ __align__(16) unsigned short xs[128][72];
    __shared__ __align__(16) unsigned short Wb[64][72];
    __shared__ int hd[128];
    int t = threadIdx.x;
    long long total = (long long)n * 64;
    long long xbase = (long long)blockIdx.x * 8192;
    if (t < 128) hd[t] = 0;
    #pragma unroll
    for (int i = 0; i < 4; ++i) {              // x: 2048 float4 chunks
        int idx = t + i * 512;                 // 0..2047
        int r = idx >> 4, c4 = (idx & 15) << 2;
        long long g = xbase + (long long)idx * 4;
        float4 v;
        if (g + 3 < total) v = *(const float4*)(x + g);
        else {
            v.x = (g + 0 < total) ? x[g + 0] : 0.f;
            v.y = (g + 1 < total) ? x[g + 1] : 0.f;
            v.z = (g + 2 < total) ? x[g + 2] : 0.f;
            v.w = (g + 3 < total) ? x[g + 3] : 0.f;
        }
        ushort4 o; o.x = f2bf(v.x); o.y = f2bf(v.y); o.z = f2bf(v.z); o.w = f2bf(v.w);
        *(ushort4*)&xs[r][c4] = o;
    }
    #pragma unroll
    for (int i = 0; i < 2; ++i) {              // W: 1024 float4 chunks
        int idx = t + i * 512;                 // 0..1023
        int r = idx >> 4, c4 = (idx & 15) << 2;
        float4 wv = *(const float4*)(W + idx * 4);     // W: 4096 floats
        ushort4 wo; wo.x = f2bf(wv.x); wo.y = f2bf(wv.y); wo.z = f2bf(wv.z); wo.w = f2bf(wv.w);
        *(ushort4*)&Wb[r][c4] = wo;
    }
    {   // degree hist for this block's 128 dests (half of the bucket)
        int bb  = blockIdx.x >> 1;             // bucket
        int sub = blockIdx.x & 1;              // which 128-dest half
        int s0 = bb * CAP;
        int count = min(gcnt[bb], CAP);
        for (int i = t; i < count; i += 512) {
            unsigned d = ebuf[s0 + i] >> 24;
            if ((int)(d >> 7) == sub) atomicAdd(&hd[d & 127], 1);
        }
    }
    __syncthreads();
    int lane = t & 63, wid = t >> 6;           // 8 waves: rows wid*16..+16
    int m  = wid * 16 + (lane & 15);
    int kg = (lane >> 4) * 8;
    bf16x8 a0 = *(bf16x8*)&xs[m][kg];
    bf16x8 a1 = *(bf16x8*)&xs[m][32 + kg];
    int bn = lane & 15;
    f32x4 acc0 = {0.f,0.f,0.f,0.f}, acc1 = acc0, acc2 = acc0, acc3 = acc0;
    {
        bf16x8 b0 = *(bf16x8*)&Wb[bn][kg], b1 = *(bf16x8*)&Wb[bn][32 + kg];
        acc0 = __builtin_amdgcn_mfma_f32_16x16x32_bf16(a0, b0, acc0, 0, 0, 0);
        acc0 = __builtin_amdgcn_mfma_f32_16x16x32_bf16(a1, b1, acc0, 0, 0, 0);
    }
    {
        bf16x8 b0 = *(bf16x8*)&Wb[bn + 16][kg], b1 = *(bf16x8*)&Wb[bn + 16][32 + kg];
        acc1 = __builtin_amdgcn_mfma_f32_16x16x32_bf16(a0, b0, acc1, 0, 0, 0);
        acc1 = __builtin_amdgcn_mfma_f32_16x16x32_bf16(a1, b1, acc1, 0, 0, 0);
    }
    {
        bf16x8 b0 = *(bf16x8*)&Wb[bn + 32][kg], b1 = *(bf16x8*)&Wb[bn + 32][32 + kg];
        acc2 = __builtin_amdgcn_mfma_f32_16x16x32_bf16(a0, b0, acc2, 0, 0, 0);
        acc2 = __builtin_amdgcn_mfma_f32_16x16x32_bf16(a1, b1, acc2, 0, 0, 0);
    }
    {
        bf16x8 b0 = *(bf16x8*)&Wb[bn + 48][kg], b1 = *(bf16x8*)&Wb[bn + 48][32 + kg];
        acc3 = __builtin_amdgcn_mfma_f32_16x16x32_bf16(a0, b0, acc3, 0, 0, 0);
        acc3 = __builtin_amdgcn_mfma_f32_16x16x32_bf16(a1, b1, acc3, 0, 0, 0);
    }
    // C/D layout: col = lane&15, row = (lane>>4)*4 + reg  [m89-verified]
    int lr0 = wid * 16 + (lane >> 4) * 4;
    int rbase = blockIdx.x * 128 + lr0;
    #pragma unroll
    for (int i = 0; i < 4; ++i) {
        int r = rbase + i;
        if (r < n) {
            float dv = rsqrtf((float)hd[lr0 + i] + 1.0f);
            long long ro = (long long)r * 64 + bn;
            yb[ro +  0] = f2bf(dv * acc0[i]);
            yb[ro + 16] = f2bf(dv * acc1[i]);
            yb[ro + 32] = f2bf(dv * acc2[i]);
            yb[ro + 48] = f2bf(dv * acc3[i]);
        }
    }
}

// FUSED sort+gather: one 1024-thread block per bucket. LDS counting sort by
// dst&255 (sbuf never leaves LDS); then each 16-lane group gathers one dest's
// src list (broadcast ds_read) and writes out directly. Dest scale computed
// locally: dc = rsqrtf(len+1).
__global__ __launch_bounds__(1024) void k_aggr(const unsigned int* __restrict__ ebuf,
                                               const int* __restrict__ gcnt,
                                               const unsigned short* __restrict__ yb,
                                               const float* __restrict__ bias,
                                               float* __restrict__ out, int n) {
    __shared__ int h[256], hstart[256], hc[256], wsum[4];
    __shared__ int sbuf[CAP];                  // 20 KB, LDS-only
    int b = blockIdx.x, t = threadIdx.x;
    int s0 = b * CAP;
    int count = min(gcnt[b], CAP);

    if (t < 256) h[t] = 0;
    __syncthreads();
    unsigned rec[5];
    #pragma unroll
    for (int k = 0; k < 5; ++k) {              // coalesced load + LDS hist
        int i = t + k * 1024;
        if (i < count) {
            unsigned p = ebuf[s0 + i];
            rec[k] = p;
            atomicAdd(&h[p >> 24], 1);
        }
    }
    __syncthreads();
    if (t < 256) {                             // wave-shfl inclusive scan
        int v = h[t];
        int lane = t & 63, wid = t >> 6;
        int incl = v;
        #pragma unroll
        for (int off = 1; off < 64; off <<= 1) {
            int u = __shfl_up(incl, off);
            if (lane >= off) incl += u;
        }
        hstart[t] = incl;                      // temp: inclusive
        if (lane == 63) wsum[wid] = incl;
    }
    __syncthreads();
    if (t < 256) {
        int wid = t >> 6;
        int add = 0;
        for (int w = 0; w < wid; ++w) add += wsum[w];
        int ex = hstart[t] - h[t] + add;       // exclusive prefix
        hstart[t] = ex;
        hc[t] = ex;
    }
    __syncthreads();
    #pragma unroll
    for (int k = 0; k < 5; ++k) {              // counting-sort scatter (LDS)
        int i = t + k * 1024;
        if (i < count) {
            unsigned p = rec[k];
            int r = atomicAdd(&hc[p >> 24], 1);
            sbuf[r] = (int)(p & 0x1FFFFu);
        }
    }
    __syncthreads();

    // Gather: 16 waves x 4 groups = 64 dest-slots; 4 rounds cover 256 dests.
    int lane = t & 63, w = t >> 6;
    int g = lane >> 4, q = lane & 15;
    #pragma unroll
    for (int r = 0; r < 4; ++r) {
        int cl = r * 64 + w * 4 + g;
        int c = b * 256 + cl;
        if (c >= n) continue;                  // no barriers below: safe
        int start = hstart[cl], len = h[cl];
        float a0 = 0.f, a1 = 0.f, a2 = 0.f, a3 = 0.f;
        if (len > 0) {
            int sc = sbuf[start];              // prefetched src
            for (int i = 0; i < len; ++i) {
                int sn = (i + 1 < len) ? sbuf[start + i + 1] : 0;
                float2 v = *(const float2*)(yb + (long long)sc * 64 + (q << 2));
                unsigned u0 = __float_as_uint(v.x), u1 = __float_as_uint(v.y);
                a0 += bflo(u0); a1 += bfhi(u0);
                a2 += bflo(u1); a3 += bfhi(u1);
                sc = sn;
            }
        }
        {   // self loop
            float2 v = *(const float2*)(yb + (long long)c * 64 + (q << 2));
            unsigned u0 = __float_as_uint(v.x), u1 = __float_as_uint(v.y);
            a0 += bflo(u0); a1 += bfhi(u0);
            a2 += bflo(u1); a3 += bfhi(u1);
        }
        float dc = rsqrtf((float)len + 1.0f);
        float4 bv = *(const float4*)(bias + (q << 2));
        *(float4*)(out + (long long)c * 64 + (q << 2)) =
            make_float4(dc * a0 + bv.x, dc * a1 + bv.y,
                        dc * a2 + bv.z, dc * a3 + bv.w);
    }
}

extern "C" void kernel_launch(void* const* d_in, const int* in_sizes, int n_in,
                              void* d_out, int out_size, void* d_ws, size_t ws_size,
                              hipStream_t stream) {
    const float* x    = (const float*)d_in[0];
    const int*   ei   = (const int*)d_in[1];
    // d_in[2] = x0 (unused: use_init=False)
    const float* W    = (const float*)d_in[3];
    const float* bias = (const float*)d_in[4];
    float* out = (float*)d_out;

    int n = in_sizes[0] / 64;
    int E = in_sizes[1] / 2;
    const int* row = ei;        // source
    const int* col = ei + E;    // target

    int NB = (n + 255) / 256;   // 391 (<= NBMAX, <= 512)

    char* ws = (char*)d_ws;
    size_t off = 0;
    auto alloc = [&](size_t bytes) { char* p = ws + off; off += (bytes + 15) & ~size_t(15); return p; };
    int*            gcnt = (int*)  alloc((size_t)NB * 4);
    unsigned short* yb   = (unsigned short*)alloc((size_t)n * 64 * 2);
    unsigned int*   ebuf = (unsigned int*)alloc((size_t)NB * CAP * 4);

    int nbE = (E + 4095) / 4096;

    hipMemsetAsync(gcnt, 0, (size_t)NB * 4, stream);
    k_bin    <<<nbE, 512, 0, stream>>>(row, col, gcnt, ebuf, E);
    k_gemmcnt<<<(n + 127) / 128, 512, 0, stream>>>(x, W, ebuf, gcnt, yb, n);
    k_aggr   <<<NB, 1024, 0, stream>>>(ebuf, gcnt, yb, bias, out, n);
}